// Round 3
// baseline (428.886 us; speedup 1.0000x reference)
//
#include <hip/hip_runtime.h>
#include <math.h>

#define N_   4
#define C_   128
#define CO_  128
#define H_   96
#define W_   96
#define HW_  (H_*W_)
#define BN_EPS_ 1e-5f

typedef short bf16x8 __attribute__((ext_vector_type(8)));
typedef float f32x4  __attribute__((ext_vector_type(4)));

__device__ __forceinline__ unsigned short f2bf_rne(float f) {
    unsigned u = __builtin_bit_cast(unsigned, f);
    return (unsigned short)((u + 0x7fffu + ((u >> 16) & 1u)) >> 16);
}
__device__ __forceinline__ float bf2f(unsigned short s) {
    unsigned u = ((unsigned)s) << 16;
    return __builtin_bit_cast(float, u);
}

// ---------------------------------------------------------------------------
// ws layout (float offsets):
//   convout : 995328 f                     @ 0
//   out_pre : 4718592 ushort (2359296 f)   @ 995328    [n][o][hw] bf16
//   bn      : 256 f                        @ 3354624
//   wjT     : 36864 ushort (18432 f)       @ 3354880   [kk][k_hi][j32][k_lo8]
//   wTA     : 147456 ushort (73728 f)      @ 3373312   [kk][k_hi][o128][k_lo8]
//   xb      : 4718592 ushort (2359296 f)   @ 3447040   [n][hw][c] channel-last bf16
// total 5806336 f = 23.2 MB
// ---------------------------------------------------------------------------
#define WS_CONVOUT 0
#define WS_OUTPRE  995328
#define WS_BN      3354624
#define WS_WJT     3354880
#define WS_WTA     3373312
#define WS_XB      3447040

// K ordering: K = ktap*128 + c, chunk kk of 32: ktap=kk>>2, c=(kk&3)*32+k_hi*8+k_lo.

// k_prep: blocks [0,1152) transpose x -> channel-last bf16; [1152,1872) repack weights.
__global__ __launch_bounds__(256)
void k_prep(const float* __restrict__ x,
            const float* __restrict__ offw, const float* __restrict__ modw,
            const float* __restrict__ weight,
            unsigned short* __restrict__ xb,
            unsigned short* __restrict__ wjT, unsigned short* __restrict__ wTA) {
    const int b = blockIdx.x;
    const int t = threadIdx.x;
    if (b < 1152) {
        __shared__ __align__(16) unsigned short lds[32][136];
        const int n = b / 288, pix0 = (b % 288) * 32;   // 32-pix tiles never straddle rows (96%32==0)
        #pragma unroll
        for (int it = 0; it < 16; ++it) {
            const int c = it*8 + (t >> 5);
            const int p = t & 31;
            lds[p][c] = f2bf_rne(x[((size_t)(n*C_ + c))*HW_ + pix0 + p]);
        }
        __syncthreads();
        #pragma unroll
        for (int it = 0; it < 2; ++it) {
            const int e = it*256 + t;
            const int p = e >> 4, g = e & 15;
            const uint4 v = *(const uint4*)&lds[p][g*8];
            *(uint4*)&xb[((size_t)n*HW_ + pix0 + p)*C_ + g*8] = v;
        }
    } else {
        const int e = (b - 1152)*256 + t;               // 184320 exact
        if (e < 36864) {
            const int k_lo = e & 7, j = (e >> 3) & 31, k_hi = (e >> 8) & 3, kk = e >> 10;
            const int c  = (kk & 3)*32 + k_hi*8 + k_lo;
            const int kt = kk >> 2;
            float v = 0.0f;
            if (j < 18)      v = offw[(j*C_ + c)*9 + kt];
            else if (j < 27) v = modw[((j-18)*C_ + c)*9 + kt];
            wjT[e] = f2bf_rne(v);
        } else {
            const int e2 = e - 36864;
            const int k_lo = e2 & 7, o = (e2 >> 3) & 127, k_hi = (e2 >> 10) & 3, kk = e2 >> 12;
            const int c  = (kk & 3)*32 + k_hi*8 + k_lo;
            const int kt = kk >> 2;
            wTA[e2] = f2bf_rne(weight[(o*C_ + c)*9 + kt]);
        }
    }
}

// k_offconv: barrier-free per-wave GEMM. Wave = 16 pixels x 32 j, K=1152.
// grid 576 blocks x 4 waves = 2304 waves.
__global__ __launch_bounds__(256)
void k_offconv(const unsigned short* __restrict__ xb,
               const unsigned short* __restrict__ wjT,
               const float* __restrict__ offb, const float* __restrict__ modb,
               float* __restrict__ convout) {
    const int t = threadIdx.x;
    const int wid = t >> 6, lane = t & 63, quad = lane >> 4, l16 = lane & 15;
    const int tile = blockIdx.x*4 + wid;
    const int n = tile / 576, pix0 = (tile - n*576)*16;
    const int pix = pix0 + l16;
    const int h = pix / W_, w = pix - h*W_;     // 16-pix tiles never straddle rows (96%16==0)
    const unsigned short* xq = xb + ((size_t)n*HW_)*C_ + quad*8;

    f32x4 acc0 = {0.f,0.f,0.f,0.f};
    f32x4 acc1 = {0.f,0.f,0.f,0.f};

    #pragma unroll
    for (int kt = 0; kt < 9; ++kt) {
        const int dy = kt/3 - 1, dx = kt%3 - 1;
        const int y = h + dy, xx = w + dx;
        const bool valid = ((unsigned)y < H_) & ((unsigned)xx < W_);
        const unsigned short* bp = xq + (size_t)(y*W_ + xx)*C_;
        #pragma unroll
        for (int s = 0; s < 4; ++s) {
            const int kk = kt*4 + s;
            const uint4 braw = valid ? *(const uint4*)(bp + s*32) : make_uint4(0u,0u,0u,0u);
            const unsigned short* ap = wjT + (size_t)(kk*4 + quad)*256 + l16*8;
            const bf16x8 a0 = *(const bf16x8*)(ap);
            const bf16x8 a1 = *(const bf16x8*)(ap + 128);
            const bf16x8 bfr = __builtin_bit_cast(bf16x8, braw);
            acc0 = __builtin_amdgcn_mfma_f32_16x16x32_bf16(a0, bfr, acc0, 0, 0, 0);
            acc1 = __builtin_amdgcn_mfma_f32_16x16x32_bf16(a1, bfr, acc1, 0, 0, 0);
        }
    }
    #pragma unroll
    for (int r = 0; r < 4; ++r) {
        const int j0 = quad*4 + r;
        convout[((size_t)n*27 + j0)*HW_ + pix] = acc0[r] + (j0 < 18 ? offb[j0] : modb[j0-18]);
        const int j1 = 16 + quad*4 + r;
        if (j1 < 27)
            convout[((size_t)n*27 + j1)*HW_ + pix] = acc1[r] + modb[j1-18];
    }
}

// k_gemm: barrier-free per-wave main GEMM. Wave = 16 pixels x 128 o, K=1152.
// Lane gathers its own B-fragment directly (no LDS). grid 576 x 4 waves.
__global__ __launch_bounds__(256)
void k_gemm(const unsigned short* __restrict__ xb,
            const float* __restrict__ convout,
            const unsigned short* __restrict__ wTA,
            unsigned short* __restrict__ out_pre,
            float* __restrict__ bnsum, float* __restrict__ bnsq) {
    const int t = threadIdx.x;
    const int wid = t >> 6, lane = t & 63, quad = lane >> 4, l16 = lane & 15;
    const int tile = blockIdx.x*4 + wid;
    const int n = tile / 576, pix0 = (tile - n*576)*16;
    const int pix = pix0 + l16;
    const int h = pix / W_, w = pix - h*W_;
    const float* co = convout + (size_t)n*27*HW_ + pix;
    const unsigned short* xq = xb + ((size_t)n*HW_)*C_ + quad*8;

    f32x4 acc[8];
    #pragma unroll
    for (int i = 0; i < 8; ++i) acc[i] = (f32x4){0.f,0.f,0.f,0.f};

    int   ibc[4], ibn[4];
    float wgc[4], wgn[4];

    // metadata for tap kt from 3 convout scalars
    #define COMPUTE_META(kt, offy, offx, mraw, ib, wg)                                   \
    {                                                                                    \
        const float m  = 2.0f / (1.0f + __expf(-(mraw)));                                \
        const float sy = (offy) + (float)(h + (kt)/3 - 1);                               \
        const float sx = (offx) + (float)(w + (kt)%3 - 1);                               \
        const float y0f = floorf(sy), x0f = floorf(sx);                                  \
        const float wy1 = sy - y0f, wx1 = sx - x0f;                                      \
        const float wyv[2] = {1.0f - wy1, wy1};                                          \
        const float wxv[2] = {1.0f - wx1, wx1};                                          \
        const float yfv[2] = {y0f, y0f + 1.0f};                                          \
        const float xfv[2] = {x0f, x0f + 1.0f};                                          \
        _Pragma("unroll")                                                                \
        for (int cyy = 0; cyy < 2; ++cyy) {                                              \
            _Pragma("unroll")                                                            \
            for (int cxx = 0; cxx < 2; ++cxx) {                                          \
                const bool vld = (yfv[cyy] >= 0.f) & (yfv[cyy] <= (float)(H_-1)) &       \
                                 (xfv[cxx] >= 0.f) & (xfv[cxx] <= (float)(W_-1));        \
                const int yi = (int)fminf(fmaxf(yfv[cyy], 0.f), (float)(H_-1));          \
                const int xi = (int)fminf(fmaxf(xfv[cxx], 0.f), (float)(W_-1));          \
                (ib)[cyy*2+cxx] = (yi*W_ + xi)*C_;                                       \
                (wg)[cyy*2+cxx] = vld ? wyv[cyy]*wxv[cxx]*m : 0.f;                       \
            }                                                                            \
        }                                                                                \
    }

    float cny, cnx, cnm;
    {
        const float a0 = co[0], a1 = co[HW_], a2 = co[18*HW_];
        COMPUTE_META(0, a0, a1, a2, ibc, wgc);
        cny = co[2*HW_]; cnx = co[3*HW_]; cnm = co[19*HW_];
    }
    uint4 g[4];
    #pragma unroll
    for (int j = 0; j < 4; ++j) g[j] = *(const uint4*)(xq + ibc[j]);

    #pragma unroll
    for (int kt = 0; kt < 9; ++kt) {
        if (kt < 8) COMPUTE_META(kt+1, cny, cnx, cnm, ibn, wgn);
        if (kt < 7) { cny = co[(2*kt+4)*HW_]; cnx = co[(2*kt+5)*HW_]; cnm = co[(20+kt)*HW_]; }
        #pragma unroll
        for (int s = 0; s < 4; ++s) {
            const int kk = kt*4 + s;
            uint4 gc[4];
            #pragma unroll
            for (int j = 0; j < 4; ++j) gc[j] = g[j];
            // prefetch next substep's gathers
            if (s < 3) {
                #pragma unroll
                for (int j = 0; j < 4; ++j) g[j] = *(const uint4*)(xq + ibc[j] + (s+1)*32);
            } else if (kt < 8) {
                #pragma unroll
                for (int j = 0; j < 4; ++j) g[j] = *(const uint4*)(xq + ibn[j]);
            }
            // A fragments (L2-hot)
            const unsigned short* ap = wTA + (size_t)(kk*4 + quad)*1024 + l16*8;
            bf16x8 a[8];
            #pragma unroll
            for (int mt = 0; mt < 8; ++mt) a[mt] = *(const bf16x8*)(ap + mt*128);
            // blend -> b-frag (truncating f32->bf16; scale bias cancels in BN)
            const unsigned short* c0 = (const unsigned short*)&gc[0];
            const unsigned short* c1 = (const unsigned short*)&gc[1];
            const unsigned short* c2 = (const unsigned short*)&gc[2];
            const unsigned short* c3 = (const unsigned short*)&gc[3];
            bf16x8 bfr;
            #pragma unroll
            for (int j = 0; j < 8; ++j) {
                const float v = wgc[0]*bf2f(c0[j]) + wgc[1]*bf2f(c1[j])
                              + wgc[2]*bf2f(c2[j]) + wgc[3]*bf2f(c3[j]);
                bfr[j] = (short)(__builtin_bit_cast(unsigned, v) >> 16);
            }
            #pragma unroll
            for (int mt = 0; mt < 8; ++mt)
                acc[mt] = __builtin_amdgcn_mfma_f32_16x16x32_bf16(a[mt], bfr, acc[mt], 0, 0, 0);
        }
        #pragma unroll
        for (int j = 0; j < 4; ++j) { ibc[j] = ibn[j]; wgc[j] = wgn[j]; }
    }

    // epilogue: store pre-BN bf16 (bias absorbed by BN), per-channel partial sums
    #pragma unroll
    for (int mt = 0; mt < 8; ++mt) {
        #pragma unroll
        for (int r = 0; r < 4; ++r) {
            const int o = mt*16 + quad*4 + r;
            const float val = acc[mt][r];
            out_pre[((size_t)n*CO_ + o)*HW_ + pix] = f2bf_rne(val);
            float s1 = val, s2 = val*val;
            #pragma unroll
            for (int d = 1; d < 16; d <<= 1) {
                s1 += __shfl_xor(s1, d);
                s2 += __shfl_xor(s2, d);
            }
            if (l16 == 0) {
                atomicAdd(&bnsum[o], s1);
                atomicAdd(&bnsq[o],  s2);
            }
        }
    }
}

// k_bn: BN finalize + ReLU. 8 bf16 in, 8 f32 out per thread.
__global__ __launch_bounds__(256)
void k_bn(const unsigned short* __restrict__ out_pre,
          const float* __restrict__ bnsum, const float* __restrict__ bnsq,
          const float* __restrict__ gamma, const float* __restrict__ beta,
          float* __restrict__ out) {
    const int e8 = blockIdx.x*256 + threadIdx.x;      // 2304 blocks exact
    const int o = ((e8*8) / HW_) % CO_;
    const float invM = 1.0f / (float)(N_*HW_);
    const float mean = bnsum[o] * invM;
    const float var  = bnsq[o] * invM - mean*mean;
    const float gsc  = gamma[o] * rsqrtf(var + BN_EPS_);
    const float sh   = beta[o] - mean * gsc;
    const uint4 v = ((const uint4*)out_pre)[e8];
    const unsigned short* us = (const unsigned short*)&v;
    float4 o0, o1;
    o0.x = fmaxf(bf2f(us[0])*gsc + sh, 0.f);
    o0.y = fmaxf(bf2f(us[1])*gsc + sh, 0.f);
    o0.z = fmaxf(bf2f(us[2])*gsc + sh, 0.f);
    o0.w = fmaxf(bf2f(us[3])*gsc + sh, 0.f);
    o1.x = fmaxf(bf2f(us[4])*gsc + sh, 0.f);
    o1.y = fmaxf(bf2f(us[5])*gsc + sh, 0.f);
    o1.z = fmaxf(bf2f(us[6])*gsc + sh, 0.f);
    o1.w = fmaxf(bf2f(us[7])*gsc + sh, 0.f);
    ((float4*)out)[e8*2]     = o0;
    ((float4*)out)[e8*2 + 1] = o1;
}

extern "C" void kernel_launch(void* const* d_in, const int* in_sizes, int n_in,
                              void* d_out, int out_size, void* d_ws, size_t ws_size,
                              hipStream_t stream) {
    const float* x      = (const float*)d_in[0];
    const float* offw   = (const float*)d_in[1];
    const float* offb   = (const float*)d_in[2];
    const float* modw   = (const float*)d_in[3];
    const float* modb   = (const float*)d_in[4];
    const float* weight = (const float*)d_in[5];
    const float* gamma  = (const float*)d_in[7];
    const float* beta   = (const float*)d_in[8];
    float* out = (float*)d_out;

    float* wsf = (float*)d_ws;
    float*          convout = wsf + WS_CONVOUT;
    unsigned short* out_pre = (unsigned short*)(wsf + WS_OUTPRE);
    float*          bn      = wsf + WS_BN;
    unsigned short* wjT     = (unsigned short*)(wsf + WS_WJT);
    unsigned short* wTA     = (unsigned short*)(wsf + WS_WTA);
    unsigned short* xb      = (unsigned short*)(wsf + WS_XB);

    hipMemsetAsync(bn, 0, 256*sizeof(float), stream);
    k_prep<<<1872, 256, 0, stream>>>(x, offw, modw, weight, xb, wjT, wTA);
    k_offconv<<<576, 256, 0, stream>>>(xb, wjT, offb, modb, convout);
    k_gemm<<<576, 256, 0, stream>>>(xb, convout, wTA, out_pre, bn, bn + 128);
    k_bn<<<2304, 256, 0, stream>>>(out_pre, bn, bn + 128, gamma, beta, out);
}

// Round 4
// 261.635 us; speedup vs baseline: 1.6393x; 1.6393x over previous
//
#include <hip/hip_runtime.h>
#include <math.h>

#define N_   4
#define C_   128
#define CO_  128
#define H_   96
#define W_   96
#define HW_  (H_*W_)
#define BN_EPS_ 1e-5f

typedef short bf16x8 __attribute__((ext_vector_type(8)));
typedef float f32x4  __attribute__((ext_vector_type(4)));
typedef unsigned short ushortx8 __attribute__((ext_vector_type(8)));

__device__ __forceinline__ unsigned short f2bf_rne(float f) {
    unsigned u = __builtin_bit_cast(unsigned, f);
    return (unsigned short)((u + 0x7fffu + ((u >> 16) & 1u)) >> 16);
}
__device__ __forceinline__ float bf2f(unsigned short s) {
    unsigned u = ((unsigned)s) << 16;
    return __builtin_bit_cast(float, u);
}

// ---------------------------------------------------------------------------
// ws layout (float offsets):
//   convout : 995328 f                     @ 0
//   out_pre : 4718592 ushort (2359296 f)   @ 995328    [n][o][hw] bf16
//   bn      : 256 f                        @ 3354624
//   wjT     : 36864 ushort (18432 f)       @ 3354880   [kk][k_hi][j32][k_lo8]
//   wTA     : 147456 ushort (73728 f)      @ 3373312   [kk][k_hi][o128][k_lo8]
//   xb      : 4718592 ushort (2359296 f)   @ 3447040   [n][hw][c] channel-last bf16
// ---------------------------------------------------------------------------
#define WS_CONVOUT 0
#define WS_OUTPRE  995328
#define WS_BN      3354624
#define WS_WJT     3354880
#define WS_WTA     3373312
#define WS_XB      3447040

// K ordering: K = ktap*128 + c, chunk kk of 32: ktap=kk>>2, c=(kk&3)*32+k_hi*8+k_lo.

// k_prep: blocks [0,1152) transpose x -> channel-last bf16; [1152,1872) repack weights.
__global__ __launch_bounds__(256)
void k_prep(const float* __restrict__ x,
            const float* __restrict__ offw, const float* __restrict__ modw,
            const float* __restrict__ weight,
            unsigned short* __restrict__ xb,
            unsigned short* __restrict__ wjT, unsigned short* __restrict__ wTA) {
    const int b = blockIdx.x;
    const int t = threadIdx.x;
    if (b < 1152) {
        __shared__ __align__(16) unsigned short lds[32][136];
        const int n = b / 288, pix0 = (b % 288) * 32;
        #pragma unroll
        for (int it = 0; it < 16; ++it) {
            const int c = it*8 + (t >> 5);
            const int p = t & 31;
            lds[p][c] = f2bf_rne(x[((size_t)(n*C_ + c))*HW_ + pix0 + p]);
        }
        __syncthreads();
        #pragma unroll
        for (int it = 0; it < 2; ++it) {
            const int e = it*256 + t;
            const int p = e >> 4, g = e & 15;
            const uint4 v = *(const uint4*)&lds[p][g*8];
            *(uint4*)&xb[((size_t)n*HW_ + pix0 + p)*C_ + g*8] = v;
        }
    } else {
        const int e = (b - 1152)*256 + t;
        if (e < 36864) {
            const int k_lo = e & 7, j = (e >> 3) & 31, k_hi = (e >> 8) & 3, kk = e >> 10;
            const int c  = (kk & 3)*32 + k_hi*8 + k_lo;
            const int kt = kk >> 2;
            float v = 0.0f;
            if (j < 18)      v = offw[(j*C_ + c)*9 + kt];
            else if (j < 27) v = modw[((j-18)*C_ + c)*9 + kt];
            wjT[e] = f2bf_rne(v);
        } else {
            const int e2 = e - 36864;
            const int k_lo = e2 & 7, o = (e2 >> 3) & 127, k_hi = (e2 >> 10) & 3, kk = e2 >> 12;
            const int c  = (kk & 3)*32 + k_hi*8 + k_lo;
            const int kt = kk >> 2;
            wTA[e2] = f2bf_rne(weight[(o*C_ + c)*9 + kt]);
        }
    }
}

// k_offconv: K-split MFMA conv. Block = 32 px; 4 waves = 2 px-halves x 2 K-halves.
// grid 1152 -> 4608 waves (~18/CU). LDS pairwise reduction at the end.
__global__ __launch_bounds__(256)
void k_offconv(const unsigned short* __restrict__ xb,
               const unsigned short* __restrict__ wjT,
               const float* __restrict__ offb, const float* __restrict__ modb,
               float* __restrict__ convout) {
    __shared__ float red[2][64][8];   // 4KB
    const int t = threadIdx.x;
    const int wid = t >> 6, lane = t & 63, quad = lane >> 4, l16 = lane & 15;
    const int ph = wid & 1, kh = wid >> 1;
    const int tile = blockIdx.x;
    const int n = tile / 288, p0 = (tile - n*288)*32;
    const int pix = p0 + ph*16 + l16;
    const int h = pix / W_, w = pix - h*W_;
    const unsigned short* xq = xb + ((size_t)n*HW_)*C_ + quad*8;

    f32x4 acc0 = {0.f,0.f,0.f,0.f};
    f32x4 acc1 = {0.f,0.f,0.f,0.f};

    #pragma unroll
    for (int i = 0; i < 18; ++i) {
        const int kk = kh*18 + i;
        const int kt = kk >> 2, s = kk & 3;
        const int dy = kt/3 - 1, dx = kt%3 - 1;
        const int y = h + dy, xx = w + dx;
        const bool valid = ((unsigned)y < H_) & ((unsigned)xx < W_);
        const uint4 braw = valid ? *(const uint4*)(xq + (size_t)(y*W_ + xx)*C_ + s*32)
                                 : make_uint4(0u,0u,0u,0u);
        const unsigned short* ap = wjT + (size_t)kk*1024 + quad*256 + l16*8;
        const bf16x8 a0 = *(const bf16x8*)(ap);
        const bf16x8 a1 = *(const bf16x8*)(ap + 128);
        const bf16x8 bfr = __builtin_bit_cast(bf16x8, braw);
        acc0 = __builtin_amdgcn_mfma_f32_16x16x32_bf16(a0, bfr, acc0, 0, 0, 0);
        acc1 = __builtin_amdgcn_mfma_f32_16x16x32_bf16(a1, bfr, acc1, 0, 0, 0);
    }

    if (kh == 1) {
        *(f32x4*)&red[ph][lane][0] = acc0;
        *(f32x4*)&red[ph][lane][4] = acc1;
    }
    __syncthreads();
    if (kh == 0) {
        const f32x4 r0 = *(const f32x4*)&red[ph][lane][0];
        const f32x4 r1 = *(const f32x4*)&red[ph][lane][4];
        #pragma unroll
        for (int r = 0; r < 4; ++r) {
            const int j0 = quad*4 + r;
            convout[((size_t)n*27 + j0)*HW_ + pix] =
                acc0[r] + r0[r] + (j0 < 18 ? offb[j0] : modb[j0-18]);
            const int j1 = 16 + quad*4 + r;
            if (j1 < 27)
                convout[((size_t)n*27 + j1)*HW_ + pix] = acc1[r] + r1[r] + modb[j1-18];
        }
    }
}

// k_gemm: LDS-staged MFMA GEMM, 32 px x 128 o per block, K=1152 (36 chunks).
// grid 1152 (4.5 blocks/CU). Wave wid owns o in [wid*32, +32).
__global__ __launch_bounds__(256)
void k_gemm(const unsigned short* __restrict__ xb,
            const float* __restrict__ convout,
            const unsigned short* __restrict__ wTA,
            unsigned short* __restrict__ out_pre,
            float* __restrict__ bnsum, float* __restrict__ bnsq) {
    __shared__ __align__(16) unsigned short Alds[4096];  // 8KB [k_hi][o128][k_lo8]
    __shared__ __align__(16) unsigned short Blds[1024];  // 2KB [k_hi][p32][k_lo8]
    __shared__ int4   midx[9][32];                        // byte offsets of 4 corners
    __shared__ float4 mwgt[9][32];

    const int t = threadIdx.x;
    const int wid = t >> 6, lane = t & 63, quad = lane >> 4, l16 = lane & 15;
    const int tile = blockIdx.x;
    const int n = tile / 288, p0 = (tile - n*288)*32;
    const char* xbn = (const char*)(xb + (size_t)n*HW_*C_);
    const float* co = convout + (size_t)n*27*HW_;

    // ---- Phase A: bilinear metadata for 9 taps x 32 pixels ----
    for (int it = t; it < 288; it += 256) {
        const int kt = it >> 5, p = it & 31;
        const int pix = p0 + p;
        const int h = pix / W_, w = pix - h*W_;
        const float offy = co[(2*kt  )*HW_ + pix];
        const float offx = co[(2*kt+1)*HW_ + pix];
        const float mraw = co[(18+kt )*HW_ + pix];
        const float m = 2.0f / (1.0f + __expf(-mraw));
        const float sy = offy + (float)(h + kt/3 - 1);
        const float sx = offx + (float)(w + kt%3 - 1);
        const float y0f = floorf(sy), x0f = floorf(sx);
        const float wy1 = sy - y0f, wx1 = sx - x0f;
        const float wyv[2] = {1.0f - wy1, wy1};
        const float wxv[2] = {1.0f - wx1, wx1};
        const float yfv[2] = {y0f, y0f + 1.0f};
        const float xfv[2] = {x0f, x0f + 1.0f};
        int   ii[4]; float ww[4];
        #pragma unroll
        for (int cy = 0; cy < 2; ++cy)
            #pragma unroll
            for (int cx = 0; cx < 2; ++cx) {
                const bool vld = (yfv[cy] >= 0.f) & (yfv[cy] <= (float)(H_-1)) &
                                 (xfv[cx] >= 0.f) & (xfv[cx] <= (float)(W_-1));
                const int yi = (int)fminf(fmaxf(yfv[cy], 0.f), (float)(H_-1));
                const int xi = (int)fminf(fmaxf(xfv[cx], 0.f), (float)(W_-1));
                ii[cy*2+cx] = (yi*W_ + xi)*C_*2;   // byte offset into xb row space
                ww[cy*2+cx] = vld ? wyv[cy]*wxv[cx]*m : 0.f;
            }
        midx[kt][p] = make_int4(ii[0], ii[1], ii[2], ii[3]);
        mwgt[kt][p] = make_float4(ww[0], ww[1], ww[2], ww[3]);
    }
    __syncthreads();

    f32x4 acc[2][2];
    #pragma unroll
    for (int i = 0; i < 2; ++i)
        #pragma unroll
        for (int j = 0; j < 2; ++j) acc[i][j] = (f32x4){0.f,0.f,0.f,0.f};

    const int bk = t & 3;      // B-stage: k_hi
    const int bp = t >> 2;     // B-stage: pixel (t<128)

    for (int kk = 0; kk < 36; ++kk) {
        // stage A: 8KB coalesced (all 256 threads, 2 x uint4)
        {
            const uint4* g = (const uint4*)(wTA + (size_t)kk*4096);
            const uint4 v0 = g[t];
            const uint4 v1 = g[t + 256];
            ((uint4*)Alds)[t]       = v0;
            ((uint4*)Alds)[t + 256] = v1;
        }
        // stage B: gather + blend (threads 0..127); 4 lanes share a corner set
        if (t < 128) {
            const int kt = kk >> 2;
            const int cb2 = ((kk & 3)*32 + bk*8)*2;
            const int4   ib = midx[kt][bp];
            const float4 wg = mwgt[kt][bp];
            const char* xc = xbn + cb2;
            const uint4 r0 = *(const uint4*)(xc + ib.x);
            const uint4 r1 = *(const uint4*)(xc + ib.y);
            const uint4 r2 = *(const uint4*)(xc + ib.z);
            const uint4 r3 = *(const uint4*)(xc + ib.w);
            const unsigned short* c0 = (const unsigned short*)&r0;
            const unsigned short* c1 = (const unsigned short*)&r1;
            const unsigned short* c2 = (const unsigned short*)&r2;
            const unsigned short* c3 = (const unsigned short*)&r3;
            ushortx8 v;
            #pragma unroll
            for (int j = 0; j < 8; ++j) {
                const float f = wg.x*bf2f(c0[j]) + wg.y*bf2f(c1[j])
                              + wg.z*bf2f(c2[j]) + wg.w*bf2f(c3[j]);
                v[j] = (unsigned short)(__builtin_bit_cast(unsigned, f) >> 16);
            }
            *(ushortx8*)&Blds[(bk*32 + bp)*8] = v;
        }
        __syncthreads();

        const bf16x8 a0 = *(const bf16x8*)&Alds[(quad*128 + wid*32 + l16)*8];
        const bf16x8 a1 = *(const bf16x8*)&Alds[(quad*128 + wid*32 + 16 + l16)*8];
        const bf16x8 b0 = *(const bf16x8*)&Blds[(quad*32 + l16)*8];
        const bf16x8 b1 = *(const bf16x8*)&Blds[(quad*32 + 16 + l16)*8];
        acc[0][0] = __builtin_amdgcn_mfma_f32_16x16x32_bf16(a0, b0, acc[0][0], 0, 0, 0);
        acc[0][1] = __builtin_amdgcn_mfma_f32_16x16x32_bf16(a0, b1, acc[0][1], 0, 0, 0);
        acc[1][0] = __builtin_amdgcn_mfma_f32_16x16x32_bf16(a1, b0, acc[1][0], 0, 0, 0);
        acc[1][1] = __builtin_amdgcn_mfma_f32_16x16x32_bf16(a1, b1, acc[1][1], 0, 0, 0);
        __syncthreads();
    }

    // ---- epilogue: store pre-BN bf16 (bias absorbed by BN), BN partial sums ----
    #pragma unroll
    for (int mt = 0; mt < 2; ++mt) {
        #pragma unroll
        for (int r = 0; r < 4; ++r) {
            const int o = wid*32 + mt*16 + quad*4 + r;
            const float v0 = acc[mt][0][r];
            const float v1 = acc[mt][1][r];
            unsigned short* op = out_pre + ((size_t)n*CO_ + o)*HW_ + p0 + l16;
            op[0]  = f2bf_rne(v0);
            op[16] = f2bf_rne(v1);
            float s1 = v0 + v1, s2 = v0*v0 + v1*v1;
            #pragma unroll
            for (int d = 1; d < 16; d <<= 1) {
                s1 += __shfl_xor(s1, d);
                s2 += __shfl_xor(s2, d);
            }
            if (l16 == 0) {
                atomicAdd(&bnsum[o], s1);
                atomicAdd(&bnsq[o],  s2);
            }
        }
    }
}

// k_bn: BN finalize + ReLU. 8 bf16 in, 8 f32 out per thread.
__global__ __launch_bounds__(256)
void k_bn(const unsigned short* __restrict__ out_pre,
          const float* __restrict__ bnsum, const float* __restrict__ bnsq,
          const float* __restrict__ gamma, const float* __restrict__ beta,
          float* __restrict__ out) {
    const int e8 = blockIdx.x*256 + threadIdx.x;
    const int o = ((e8*8) / HW_) % CO_;
    const float invM = 1.0f / (float)(N_*HW_);
    const float mean = bnsum[o] * invM;
    const float var  = bnsq[o] * invM - mean*mean;
    const float gsc  = gamma[o] * rsqrtf(var + BN_EPS_);
    const float sh   = beta[o] - mean * gsc;
    const uint4 v = ((const uint4*)out_pre)[e8];
    const unsigned short* us = (const unsigned short*)&v;
    float4 o0, o1;
    o0.x = fmaxf(bf2f(us[0])*gsc + sh, 0.f);
    o0.y = fmaxf(bf2f(us[1])*gsc + sh, 0.f);
    o0.z = fmaxf(bf2f(us[2])*gsc + sh, 0.f);
    o0.w = fmaxf(bf2f(us[3])*gsc + sh, 0.f);
    o1.x = fmaxf(bf2f(us[4])*gsc + sh, 0.f);
    o1.y = fmaxf(bf2f(us[5])*gsc + sh, 0.f);
    o1.z = fmaxf(bf2f(us[6])*gsc + sh, 0.f);
    o1.w = fmaxf(bf2f(us[7])*gsc + sh, 0.f);
    ((float4*)out)[e8*2]     = o0;
    ((float4*)out)[e8*2 + 1] = o1;
}

extern "C" void kernel_launch(void* const* d_in, const int* in_sizes, int n_in,
                              void* d_out, int out_size, void* d_ws, size_t ws_size,
                              hipStream_t stream) {
    const float* x      = (const float*)d_in[0];
    const float* offw   = (const float*)d_in[1];
    const float* offb   = (const float*)d_in[2];
    const float* modw   = (const float*)d_in[3];
    const float* modb   = (const float*)d_in[4];
    const float* weight = (const float*)d_in[5];
    const float* gamma  = (const float*)d_in[7];
    const float* beta   = (const float*)d_in[8];
    float* out = (float*)d_out;

    float* wsf = (float*)d_ws;
    float*          convout = wsf + WS_CONVOUT;
    unsigned short* out_pre = (unsigned short*)(wsf + WS_OUTPRE);
    float*          bn      = wsf + WS_BN;
    unsigned short* wjT     = (unsigned short*)(wsf + WS_WJT);
    unsigned short* wTA     = (unsigned short*)(wsf + WS_WTA);
    unsigned short* xb      = (unsigned short*)(wsf + WS_XB);

    hipMemsetAsync(bn, 0, 256*sizeof(float), stream);
    k_prep<<<1872, 256, 0, stream>>>(x, offw, modw, weight, xb, wjT, wTA);
    k_offconv<<<1152, 256, 0, stream>>>(xb, wjT, offb, modb, convout);
    k_gemm<<<1152, 256, 0, stream>>>(xb, convout, wTA, out_pre, bn, bn + 128);
    k_bn<<<2304, 256, 0, stream>>>(out_pre, bn, bn + 128, gamma, beta, out);
}